// Round 1
// baseline (555.262 us; speedup 1.0000x reference)
//
#include <hip/hip_runtime.h>
#include <math.h>

#define B_  8
#define L_  2500
#define D_  512
#define Y_  8921
#define LP  2560    // L padded
#define YP  8960    // Y padded to 140*64

// ws layout: fp16 X[B_][LP][D_]
//          | G fragment-major: [yt(140)][kk2(16)][mi(8)][lane(64)][8]
//            (G row pairs U (sub 0-7) / F (sub 8-15) per 16-row group)
// then fp32  denG[B_][YP] | numG[B_][YP]
#define WS_F16_HALVES  (B_ * LP * D_ + 2 * YP * D_)
#define ACC_FLOATS     (2 * B_ * YP)

typedef _Float16 f16x8 __attribute__((ext_vector_type(8)));
typedef float    f32x4 __attribute__((ext_vector_type(4)));

__device__ __forceinline__ void load_lds16(const _Float16* g, _Float16* l) {
  __builtin_amdgcn_global_load_lds(
      (const __attribute__((address_space(1))) unsigned int*)g,
      (__attribute__((address_space(3))) unsigned int*)l, 16, 0, 0);
}

__global__ void k_convert(const float* __restrict__ x,
                          const float* __restrict__ Uw,
                          const float* __restrict__ Fw,
                          _Float16* __restrict__ ws,
                          float* __restrict__ loss_slot) {
  if (blockIdx.x == 0 && threadIdx.x == 0) *loss_slot = 0.0f;
  const int NX = B_ * LP * (D_ / 8);   // 1310720 slots
  int idx = blockIdx.x * 256 + threadIdx.x;
  if (idx < ACC_FLOATS) ((float*)(ws + WS_F16_HALVES))[idx] = 0.0f;
  const float* src = nullptr;
  if (idx < NX) {
    int b  = idx / (LP * 64);
    int r  = idx - b * (LP * 64);
    int l  = r >> 6;
    int d8 = r & 63;
    if (l < L_) src = x + (((long)b * L_ + l) * D_ + d8 * 8);
  } else {
    // G fragment-major slot: [yt][kk2][mi][lane]
    int u    = idx - NX;
    int lane = u & 63;
    int mi   = (u >> 6) & 7;
    int kk2  = (u >> 9) & 15;
    int yt   = u >> 13;
    int grow = yt * 128 + mi * 16 + (lane & 15);   // global G row
    int sub  = grow & 15;
    int y    = (grow >> 4) * 8 + (sub & 7);
    int k8   = kk2 * 4 + (lane >> 4);              // 8-elem k granule
    if (y < Y_) src = (sub < 8 ? Uw : Fw) + (long)y * D_ + k8 * 8;
  }
  f16x8 o;
  if (src) {
    const float4* s4 = (const float4*)src;
    float4 a = s4[0], c = s4[1];
    o[0] = (_Float16)a.x; o[1] = (_Float16)a.y; o[2] = (_Float16)a.z; o[3] = (_Float16)a.w;
    o[4] = (_Float16)c.x; o[5] = (_Float16)c.y; o[6] = (_Float16)c.z; o[7] = (_Float16)c.w;
  } else {
    for (int i = 0; i < 8; ++i) o[i] = (_Float16)0.0f;
  }
  ((f16x8*)ws)[idx] = o;
}

// Interleaved-G fused attention, A-operand direct from global.
// NEW in this round: double-buffered X staging with a counted
// s_waitcnt vmcnt(8) pipeline (T3/T4) + s_setprio around the MFMA cluster
// (T5). Per K-step: issue au loads, issue next-step stage into buf^1,
// vmcnt(8) (au + cur stage complete, next stage stays IN FLIGHT across the
// barrier), raw s_barrier, ds_read+MFMA, raw s_barrier. No vmcnt(0) drain
// anywhere in the main loop. Tail kept uniform via a dummy re-stage so the
// waitcnt pass doesn't see a CFG merge and pessimize to vmcnt(0).
__global__ __launch_bounds__(256, 2)
void k_attn(const _Float16* __restrict__ ws,
            float* __restrict__ accG) {
  __shared__ __align__(16) _Float16 XT[2][16384];   // 2 x (256 rows x 64 halves)

  const int tid  = threadIdx.x;
  const int lane = tid & 63;
  const int wave = tid >> 6;           // 0..3
  const int wy = wave & 1;             // G-half (64 G rows = 32 y)
  const int wl = wave >> 1;            // l-half (128 cols)
  const int yt = blockIdx.x;           // 0..139 (64 labels each)
  const int b  = blockIdx.y;
  const int lh = blockIdx.z;

  const _Float16* Xg = ws + (long)b * LP * D_ + (long)lh * (LP / 2) * D_;
  // fragment-major G base for this yt block + this wave's row-half + lane
  const _Float16* Ga = ws + (long)B_ * LP * D_ + (long)yt * (128 * 512)
                          + (wy * 4) * 512 + lane * 8;

  // X staging: 32 segments of 1KB (8 rows x 64 halves); 8 per wave.
  // xsrc_i = xbase + i*4096 (+ step offset); xdst_i = lbase + buf*16384 + i*512
  const int srow = lane >> 3;
  const int sg8  = ((lane & 7) ^ srow) * 8;
  const _Float16* xbase = Xg + (long)(wave * 64 + srow) * D_ + sg8;
  _Float16* lbase = &XT[0][wave * 4096];

  // compute geometry
  const int xrow = wl * 128 + (lane & 15);
  const int r7   = lane & 7;
  const int gb   = lane >> 4;
  const bool sLow = (lane < 32);

  float redP[4][4];   // den partials (lanes 0-31) / num partials (lanes 32-63)
  #pragma unroll
  for (int i = 0; i < 4; ++i)
    for (int v = 0; v < 4; ++v) redP[i][v] = 0.0f;

  // prologue: stage step 0 into buffer 0 (completion covered by the first
  // in-loop vmcnt(8) + barrier)
  #pragma unroll
  for (int i = 0; i < 8; ++i)
    load_lds16(xbase + i * 4096, lbase + i * 512);

  for (int lt = 0; lt < 5; ++lt) {
    f32x4 acc[4][8];
    #pragma unroll
    for (int mi = 0; mi < 4; ++mi)
      for (int ni = 0; ni < 8; ++ni) {
        f32x4 z = {0.0f, 0.0f, 0.0f, 0.0f};
        acc[mi][ni] = z;
      }
    #pragma unroll 2
    for (int kk = 0; kk < 8; ++kk) {
      const int s   = lt * 8 + kk;
      const int cur = kk & 1;          // lt*8 is even -> parity folds
      // A-fragments direct from global (L2) — issued FIRST so one counted
      // vmcnt(8) covers both au and the cur-buffer stage.
      f16x8 au[2][4];
      #pragma unroll
      for (int ks = 0; ks < 2; ++ks)
        #pragma unroll
        for (int mi = 0; mi < 4; ++mi)
          au[ks][mi] = *(const f16x8*)(Ga + (size_t)(kk * 2 + ks) * 4096 + mi * 512);
      __builtin_amdgcn_sched_barrier(0);   // pin: au issued before the stage
      // prefetch next step's X tile into the other buffer. The buffer being
      // written (cur^1) was last read at step s-1; the end-of-(s-1) barrier
      // makes this write safe. Tail: dummy re-stage of step 39 into the
      // dead buffer keeps the loop body (and waitcnt analysis) uniform.
      {
        const int  sp  = (s < 39) ? s + 1 : 39;
        const long ofs = (long)(sp >> 3) * (256 * D_) + (long)(sp & 7) * 64;
        _Float16* dst = lbase + (cur ^ 1) * 16384;
        #pragma unroll
        for (int i = 0; i < 8; ++i)
          load_lds16(xbase + ofs + i * 4096, dst + i * 512);
      }
      // counted wait: exactly the 8 loads just issued may remain in flight;
      // everything older (cur stage + au) is complete. NOT vmcnt(0).
      asm volatile("s_waitcnt vmcnt(8)" ::: "memory");
      __builtin_amdgcn_s_barrier();
      __builtin_amdgcn_sched_barrier(0);   // keep ds_reads below the barrier
      __builtin_amdgcn_s_setprio(1);
      #pragma unroll
      for (int ks = 0; ks < 2; ++ks) {
        const int off = (((ks * 4 + gb) ^ r7) * 8);
        f16x8 bx[8];
        #pragma unroll
        for (int ni = 0; ni < 8; ++ni)
          bx[ni] = *(const f16x8*)&XT[cur][(xrow + ni * 16) * 64 + off];
        #pragma unroll
        for (int mi = 0; mi < 4; ++mi)
          #pragma unroll
          for (int ni = 0; ni < 8; ++ni)
            acc[mi][ni] = __builtin_amdgcn_mfma_f32_16x16x32_f16(au[ks][mi], bx[ni], acc[mi][ni], 0, 0, 0);
      }
      __builtin_amdgcn_s_setprio(0);
      if (kk == 7) {
        // epilogue: low lanes hold S -> e=exp(S), den += e; shfl_xor(e,32)
        // hands e to the C half; upper lanes num += e * C. Runs while the
        // next lt's first stage is in flight. Pad cols: e=1 exact, C=0.
        #pragma unroll
        for (int mi = 0; mi < 4; ++mi)
          for (int ni = 0; ni < 8; ++ni)
            #pragma unroll
            for (int v = 0; v < 4; ++v) {
              float a = acc[mi][ni][v];
              float e = __expf(a);
              float p = __shfl_xor(e, 32, 64);
              redP[mi][v] += sLow ? e : p * a;
            }
      }
      __builtin_amdgcn_s_barrier();   // reads of buf[cur] done before s+1 overwrites it
    }
  }

  // reduce over the 16 columns sharing each label row
  for (int m = 1; m < 16; m <<= 1)
    #pragma unroll
    for (int mi = 0; mi < 4; ++mi)
      for (int v = 0; v < 4; ++v)
        redP[mi][v] += __shfl_xor(redP[mi][v], m, 64);
  if ((lane & 15) == 0) {
    float* dst = accG + (sLow ? 0 : B_ * YP);   // den | num
    #pragma unroll
    for (int mi = 0; mi < 4; ++mi)
      for (int v = 0; v < 4; ++v) {
        int y = yt * 64 + wy * 32 + mi * 8 + ((lane >> 4) & 1) * 4 + v;
        atomicAdd(&dst[b * YP + y], redP[mi][v]);
      }
  }
}

__global__ void k_final(const float* __restrict__ accG,
                        const float* __restrict__ fb,
                        float* __restrict__ out) {
  int id = blockIdx.x * 256 + threadIdx.x;
  if (id >= B_ * Y_) return;
  int b = id / Y_, y = id - b * Y_;
  float den = accG[b * YP + y] - (float)(LP - L_);
  out[id] = accG[B_ * YP + b * YP + y] / den + fb[y];
}

__global__ void k_loss(const float* __restrict__ y,
                       const float* __restrict__ t,
                       float* __restrict__ loss) {
  float p = 0.0f;
  for (int i = blockIdx.x * 256 + threadIdx.x; i < B_ * Y_; i += gridDim.x * 256) {
    float v = y[i], tg = t[i];
    p += fmaxf(v, 0.0f) - v * tg + log1pf(__expf(-fabsf(v)));
  }
  for (int m = 32; m; m >>= 1) p += __shfl_down(p, m, 64);
  __shared__ float wsum[4];
  int lane = threadIdx.x & 63, wv = threadIdx.x >> 6;
  if (lane == 0) wsum[wv] = p;
  __syncthreads();
  if (threadIdx.x == 0) {
    float s = wsum[0] + wsum[1] + wsum[2] + wsum[3];
    atomicAdd(loss, s * (1.0f / (float)(B_ * Y_)));
  }
}

extern "C" void kernel_launch(void* const* d_in, const int* in_sizes, int n_in,
                              void* d_out, int out_size, void* d_ws, size_t ws_size,
                              hipStream_t stream) {
  (void)in_sizes; (void)n_in; (void)out_size; (void)ws_size;
  const float* x       = (const float*)d_in[0];
  const float* target  = (const float*)d_in[1];
  const float* U_w     = (const float*)d_in[3];
  const float* final_w = (const float*)d_in[4];
  const float* final_b = (const float*)d_in[5];
  float* out = (float*)d_out;
  _Float16* ws = (_Float16*)d_ws;
  float* accG = (float*)(ws + WS_F16_HALVES);

  k_convert<<<9600, 256, 0, stream>>>(x, U_w, final_w, ws, out + B_ * Y_);

  dim3 g(YP / 64, B_, 2);
  k_attn<<<g, 256, 0, stream>>>(ws, accG);

  k_final<<<(B_ * Y_ + 255) / 256, 256, 0, stream>>>(accG, final_b, out);
  k_loss<<<140, 256, 0, stream>>>(out, target, out + B_ * Y_);
}